// Round 1
// baseline (394.146 us; speedup 1.0000x reference)
//
#include <hip/hip_runtime.h>
#include <cmath>

#define Bq 64
#define Qn 900
#define Tn 100
#define Cn 92
#define NT 256
#define INFN 1e9f

// ---------------- Kernel A: cost matrix [B,Q,T] ----------------
__global__ __launch_bounds__(128) void cost_kernel(
        const float* __restrict__ logits,      // [B,Q,C]
        const float* __restrict__ pred_bbox,   // [B,Q,4]
        const int*   __restrict__ tgt_labels,  // [B,T]
        const float* __restrict__ tgt_bbox,    // [B,T,4]
        float* __restrict__ out_cost)          // [B,Q,T]
{
    const int bq = blockIdx.x;           // b*Q + q
    const int b  = bq / Qn;
    const int t  = threadIdx.x;

    __shared__ float ex[Cn];
    __shared__ float red[128];

    float lg = (t < Cn) ? logits[(size_t)bq * Cn + t] : -3.0e38f;
    red[t] = lg;
    __syncthreads();
    for (int off = 64; off > 0; off >>= 1) {
        if (t < off) red[t] = fmaxf(red[t], red[t + off]);
        __syncthreads();
    }
    float mx = red[0];
    __syncthreads();
    float e = (t < Cn) ? expf(lg - mx) : 0.0f;
    if (t < Cn) ex[t] = e;
    red[t] = e;
    __syncthreads();
    for (int off = 64; off > 0; off >>= 1) {
        if (t < off) red[t] += red[t + off];
        __syncthreads();
    }
    float ssum = red[0];

    if (t < Tn) {
        const float* pb = pred_bbox + (size_t)bq * 4;
        float pcx = pb[0], pcy = pb[1], pw = pb[2], ph = pb[3];
        const float* tb = tgt_bbox + ((size_t)b * Tn + t) * 4;
        float tcx = tb[0], tcy = tb[1], tw = tb[2], th = tb[3];
        int lab = tgt_labels[b * Tn + t];

        float cclass = -(ex[lab] / ssum);
        float cbbox  = fabsf(pcx - tcx) + fabsf(pcy - tcy)
                     + fabsf(pw - tw)  + fabsf(ph - th);

        float px1 = pcx - 0.5f * pw, py1 = pcy - 0.5f * ph;
        float px2 = pcx + 0.5f * pw, py2 = pcy + 0.5f * ph;
        float tx1 = tcx - 0.5f * tw, ty1 = tcy - 0.5f * th;
        float tx2 = tcx + 0.5f * tw, ty2 = tcy + 0.5f * th;

        float a1 = (px2 - px1) * (py2 - py1);
        float a2 = (tx2 - tx1) * (ty2 - ty1);
        float ltx = fmaxf(px1, tx1), lty = fmaxf(py1, ty1);
        float rbx = fminf(px2, tx2), rby = fminf(py2, ty2);
        float iw = fmaxf(rbx - ltx, 0.0f), ih = fmaxf(rby - lty, 0.0f);
        float inter = iw * ih;
        float uni = a1 + a2 - inter;
        float iou = inter / uni;
        float ex1 = fminf(px1, tx1), ey1 = fminf(py1, ty1);
        float ex2 = fmaxf(px2, tx2), ey2 = fmaxf(py2, ty2);
        float ew = fmaxf(ex2 - ex1, 0.0f), eh = fmaxf(ey2 - ey1, 0.0f);
        float ae = ew * eh;
        float giou = iou - (ae - uni) / ae;

        out_cost[(size_t)bq * Tn + t] = cbbox + cclass - giou;
    }
}

// ---------------- Kernel B: JV assignment, one block per batch ----------------
// Solves LSA on cost^T [n=100 targets, m=900 queries], mirroring the reference
// (INF=1e9, first-index argmin tie-break). Per-column state lives in LDS.
__global__ __launch_bounds__(NT) void jv_kernel(
        const float* __restrict__ cost,   // [B,Q,T] — read transposed
        float* __restrict__ out)          // full d_out
{
    const int b   = blockIdx.x;
    const int tid = threadIdx.x;
    const int Mm = Qn;   // 900 columns
    const int Nn = Tn;   // 100 rows

    __shared__ float v[Qn + 1];
    __shared__ float minv[Qn + 1];
    __shared__ int   way[Qn + 1];
    __shared__ int   p[Qn + 1];
    __shared__ unsigned char used[Qn + 1];
    __shared__ float u[Tn + 1];
    __shared__ float redv[NT / 64];
    __shared__ int   redj[NT / 64];
    __shared__ float sh_delta;
    __shared__ int   sh_j0;
    __shared__ int   qarr[Tn];

    for (int j = tid; j <= Mm; j += NT) { v[j] = 0.0f; p[j] = 0; }
    if (tid <= Nn) u[tid] = 0.0f;
    __syncthreads();

    const float* cb = cost + (size_t)b * Qn * Tn;

    for (int i = 0; i < Nn; ++i) {
        if (tid == 0) { p[0] = i + 1; sh_j0 = 0; }
        for (int j = tid; j <= Mm; j += NT) {
            minv[j] = INFN; used[j] = 0; way[j] = 0;
        }
        __syncthreads();

        int guard = 0;
        while (true) {
            int j0 = sh_j0;
            if (p[j0] == 0) break;
            if (++guard > Nn + 8) break;   // safety (legal max = n+1 iters)
            used[j0] = 1;                  // same value from all lanes: benign
            int i0 = p[j0];
            float ui0 = u[i0];
            const float* crow = cb + (i0 - 1);   // col j -> crow[(j-1)*Tn]

            float bestv = 2.0f * INFN;
            int   bestj = 0x7fffffff;
            for (int j = tid + 1; j <= Mm; j += NT) {
                if (!used[j]) {
                    float cur = crow[(size_t)(j - 1) * Tn] - ui0 - v[j];
                    float mv = minv[j];
                    if (cur < mv) { mv = cur; minv[j] = cur; way[j] = j0; }
                    if (mv < bestv || (mv == bestv && j < bestj)) { bestv = mv; bestj = j; }
                }
            }
            for (int off = 32; off > 0; off >>= 1) {
                float ov = __shfl_down(bestv, off);
                int   oj = __shfl_down(bestj, off);
                if (ov < bestv || (ov == bestv && oj < bestj)) { bestv = ov; bestj = oj; }
            }
            if ((tid & 63) == 0) { redv[tid >> 6] = bestv; redj[tid >> 6] = bestj; }
            __syncthreads();
            if (tid == 0) {
                float dv = redv[0]; int dj = redj[0];
                for (int w = 1; w < NT / 64; ++w) {
                    if (redv[w] < dv || (redv[w] == dv && redj[w] < dj)) {
                        dv = redv[w]; dj = redj[w];
                    }
                }
                sh_delta = dv; sh_j0 = dj;
            }
            __syncthreads();
            float delta = sh_delta;
            for (int j = tid; j <= Mm; j += NT) {
                if (used[j]) { u[p[j]] += delta; v[j] -= delta; }
                else          minv[j] -= delta;
            }
            __syncthreads();
        }

        if (tid == 0) {      // augment along parent pointers
            int jj = sh_j0;
            while (jj != 0) { int j1 = way[jj]; p[jj] = p[j1]; jj = j1; }
        }
        __syncthreads();
    }

    for (int j = tid + 1; j <= Mm; j += NT) {
        int r = p[j];
        if (r) qarr[r - 1] = j - 1;
    }
    __syncthreads();

    float* out_row = out + (size_t)Bq * Qn * Tn + (size_t)b * Tn;
    float* out_col = out_row + (size_t)Bq * Tn;
    for (int i = tid; i < Nn; i += NT) {
        int qi = qarr[i];
        int rank = 0;
        for (int jj = 0; jj < Nn; ++jj) rank += (qarr[jj] < qi) ? 1 : 0;
        out_row[rank] = (float)qi;   // row_ind: sorted query indices
        out_col[rank] = (float)i;    // col_ind: matched target indices
    }
}

extern "C" void kernel_launch(void* const* d_in, const int* in_sizes, int n_in,
                              void* d_out, int out_size, void* d_ws, size_t ws_size,
                              hipStream_t stream) {
    const float* logits     = (const float*)d_in[0];
    const float* pred_bbox  = (const float*)d_in[1];
    const int*   tgt_labels = (const int*)d_in[2];
    const float* tgt_bbox   = (const float*)d_in[3];
    float* out = (float*)d_out;

    hipLaunchKernelGGL(cost_kernel, dim3(Bq * Qn), dim3(128), 0, stream,
                       logits, pred_bbox, tgt_labels, tgt_bbox, out);
    hipLaunchKernelGGL(jv_kernel, dim3(Bq), dim3(NT), 0, stream, out, out);
}